// Round 7
// baseline (5674.220 us; speedup 1.0000x reference)
//
#include <hip/hip_runtime.h>

// LSTM forward, persistent-kernel, R7:
//   R6 post-mortem: latency-chain bound (~5 LLC round trips + 2 block-wide
//   barrier drains per step); FETCH_SIZE fell 3.2x but time only 6%. R7 makes
//   each wave autonomous (N-split => nothing shared intra-block):
//   - NO __syncthreads in the loop. Per-wave flags: publish -> wave-local
//     vmcnt(0) -> own flag store. Consumers poll 128 producer-wave flags
//     (2 per lane, single round trip when ready). Waves skew freely.
//   - H direct to VGPRs in rolling flights of 4 kc (32 regs in flight),
//     consumed as they land (R3 redux, but with ~190 spare VGPRs it works).
//   - Publication: 256B private-LDS transpose -> 16 lanes x one 16B sc1
//     store. sched_barrier + explicit vmcnt(0) pin store->flag order
//     (relaxed atomics only; agent-release would emit buffer_wbl2 = R1 bug).

#define NB   128
#define SEQ  512
#define BATCH 64
#define DIM  256
#define HU   1024

typedef unsigned short u16;
typedef unsigned int   u32;
typedef unsigned long long u64;
typedef __attribute__((ext_vector_type(8))) short  short8;
typedef __attribute__((ext_vector_type(4))) float  f32x4;

#define AL_RLX(p)    __hip_atomic_load((p),  __ATOMIC_RELAXED, __HIP_MEMORY_SCOPE_AGENT)
#define AS_RLX(p, v) __hip_atomic_store((p), (v), __ATOMIC_RELAXED, __HIP_MEMORY_SCOPE_AGENT)

__device__ __forceinline__ u16 f2bf(float x) {
  u32 u = __float_as_uint(x);
  u32 r = (u + 0x7FFFu + ((u >> 16) & 1u)) >> 16;   // RNE
  return (u16)r;
}
__device__ __forceinline__ float sigf(float x)  { return 1.0f / (1.0f + __expf(-x)); }
__device__ __forceinline__ float tanhfast(float x) { return 1.0f - 2.0f / (1.0f + __expf(2.0f * x)); }
__device__ __forceinline__ short8 cv8(uint4 v) {
  union { uint4 d; short8 s; } u; u.d = v; return u.s;
}
__device__ __forceinline__ short8 mk8(u64 lo, u64 hi) {
  union { u64 d[2]; short8 s; } u; u.d[0] = lo; u.d[1] = hi; return u.s;
}

// ---------------- prologue kernels ----------------

__global__ void k_prep(const float* __restrict__ H0, u16* __restrict__ Hbuf0,
                       u32* __restrict__ flags) {
  int i = blockIdx.x * 256 + threadIdx.x;
  if (i < 8192) flags[i] = 0u;              // 512 wave-flags x stride 16
  Hbuf0[i] = f2bf(H0[i]);                   // i < 65536 == BATCH*HU
}

__global__ void k_xconv(const float* __restrict__ in, u16* __restrict__ out) {
  int i = blockIdx.x * 256 + threadIdx.x;
  float4 v = ((const float4*)in)[i];
  ushort4 o;
  o.x = f2bf(v.x); o.y = f2bf(v.y); o.z = f2bf(v.z); o.w = f2bf(v.w);
  ((ushort4*)out)[i] = o;
}

// Wpack[bj(32)][nt(8)][kc(40)][lane(64)][8] bf16 : MFMA B-fragment order.
// local col c = nt*16 + (lane&15) in [0,128):
//   gate=(c>>3)&3, h = bj*32 + (c>>5)*8 + (c&7)
__global__ void k_pack(const float* __restrict__ Wxi, const float* __restrict__ Whi,
                       const float* __restrict__ Wxf, const float* __restrict__ Whf,
                       const float* __restrict__ Wxo, const float* __restrict__ Who,
                       const float* __restrict__ Wxc, const float* __restrict__ Whc,
                       u16* __restrict__ Wpack) {
  int tid  = blockIdx.x * 256 + threadIdx.x;   // < 32*8*40*64 = 655360
  int lane = tid & 63;
  int kc   = (tid >> 6) % 40;
  int nt   = ((tid >> 6) / 40) & 7;
  int bj   = (tid >> 6) / 320;
  int c    = nt * 16 + (lane & 15);
  int gate = (c >> 3) & 3;
  int h    = bj * 32 + (c >> 5) * 8 + (c & 7);
  const float* Wx = (gate == 0) ? Wxi : (gate == 1) ? Wxf : (gate == 2) ? Wxo : Wxc;
  const float* Wh = (gate == 0) ? Whi : (gate == 1) ? Whf : (gate == 2) ? Who : Whc;
  int kbase = kc * 32 + ((lane >> 4) << 3);
  u16 tmp[8];
#pragma unroll
  for (int e = 0; e < 8; e++) {
    int k = kbase + e;
    float v = (k < DIM) ? Wx[k * HU + h] : Wh[(k - DIM) * HU + h];
    tmp[e] = f2bf(v);
  }
  *(uint4*)(Wpack + (size_t)tid * 8) = *(uint4*)tmp;
}

// pred[b,t] = bd + sum_{g<128} part[t*8192 + g*64 + b];  32768 threads
__global__ void k_predsum(const float* __restrict__ part, const float* __restrict__ bd,
                          float* __restrict__ pred) {
  int i = blockIdx.x * 256 + threadIdx.x;
  int b = i & 63, t = i >> 6;
  float s = bd[0];
  const float* p0 = part + (size_t)t * NB * 64 + b;
#pragma unroll 8
  for (int jj = 0; jj < NB; jj++) s += p0[jj * 64];
  pred[b * SEQ + t] = s;
}

// ---------------- main persistent kernel ----------------

struct MainParams {
  const u16* __restrict__ xbf;     // (B,S,D) bf16
  const u16* __restrict__ Wpack;   // [32][8][40][64][8] bf16
  u16* __restrict__ Hbuf;          // [2][B][HU] bf16 (double buffer)
  const float* __restrict__ C0;
  const float* __restrict__ Wd;
  const float* __restrict__ bi;
  const float* __restrict__ bfg;
  const float* __restrict__ bo;
  const float* __restrict__ bc;
  float* __restrict__ ppart;       // [SEQ][32bj][4wv][64b] pred partials
  float* __restrict__ Hf;          // [B][HU]
  float* __restrict__ Cf;          // [B][HU]
  u32* __restrict__ flags;         // [4bb][32bj][4wv] stride-16 u32
};

__global__ __launch_bounds__(256, 1) void lstm_main(MainParams p) {
  __shared__ u16 Hpub[4 * 128];            // 1KB: per-wave 16x8 publish tile

  const int tid  = threadIdx.x;
  const int wv   = tid >> 6, lane = tid & 63;
  const int bj   = blockIdx.x >> 2, bb = blockIdx.x & 3;
  const int q    = lane >> 4;              // row quad
  const int q8   = q * 8;                  // k sub-offset in frag
  const int m16  = lane & 15;
  const int hl   = lane & 7;
  const bool hiH = (lane & 8) != 0;        // f/c-holder half

  const int hglob = bj * 32 + wv * 8 + hl; // this thread's h column
  const int row0  = 16 * bb;               // block's first batch row

  // resident weight B-fragments: wave wv owns n-tiles {2wv, 2wv+1}, full K.
  short8 wx[8][2], wh[32][2];
  {
    const u16* wbase = p.Wpack + ((size_t)bj * 8 + 2 * wv) * (40 * 512) + lane * 8;
#pragma unroll
    for (int kc = 0; kc < 8; kc++)
#pragma unroll
      for (int ntl = 0; ntl < 2; ntl++)
        wx[kc][ntl] = *(const short8*)(wbase + ((size_t)ntl * 40 + kc) * 512);
#pragma unroll
    for (int kc = 0; kc < 32; kc++)
#pragma unroll
      for (int ntl = 0; ntl < 2; ntl++)
        wh[kc][ntl] = *(const short8*)(wbase + ((size_t)ntl * 40 + 8 + kc) * 512);
  }

  // per-thread epilogue state: 4 rows (q*4+r), one h
  const float bI = p.bi[hglob],  bF = p.bfg[hglob];
  const float bO = p.bo[hglob],  bC = p.bc[hglob];
  const float wdv = p.Wd[hglob];
  float Cst[4], Hst[4];
#pragma unroll
  for (int r = 0; r < 4; r++) {
    Cst[r] = p.C0[(row0 + q * 4 + r) * HU + hglob];
    Hst[r] = 0.f;
  }

  // x fragments for t=0
  uint4 ax[8];
#pragma unroll
  for (int kc = 0; kc < 8; kc++)
    ax[kc] = *(const uint4*)(p.xbf + ((size_t)((row0 + m16) * SEQ + 0)) * DIM
                             + kc * 32 + q8);

  const u32* fbase = p.flags + (size_t)bb * 128 * 16;
  u32* myflag = p.flags + ((size_t)(bb * 32 + bj) * 4 + wv) * 16;

#pragma unroll 1
  for (int t = 0; t < SEQ; t++) {
    const int rb = t & 1;
    const u16* Hr = p.Hbuf + (size_t)rb * (BATCH * HU);
    u16*       Hw = p.Hbuf + (size_t)(rb ^ 1) * (BATCH * HU);

    // ---- poll: all 128 producer-wave flags of this bb >= t (H_t ready) ----
    {
      const u32 tgt = (u32)t;
      while (true) {
        u32 a = AL_RLX(fbase + (size_t)lane * 16);
        u32 b = AL_RLX(fbase + (size_t)(lane + 64) * 16);
        if (__all((a >= tgt) && (b >= tgt))) break;
      }
    }

    // ---- rolling H flights: 8 groups of 4 kc; issue g0,g1 now ----
    const u16* Arow = Hr + (size_t)(row0 + m16) * HU + q8;
    u64 ah[2][4][2];
#pragma unroll
    for (int kcl = 0; kcl < 4; kcl++) {
      const u64* hp = (const u64*)(Arow + (0 * 4 + kcl) * 32);
      ah[0][kcl][0] = AL_RLX(hp); ah[0][kcl][1] = AL_RLX(hp + 1);
    }
#pragma unroll
    for (int kcl = 0; kcl < 4; kcl++) {
      const u64* hp = (const u64*)(Arow + (1 * 4 + kcl) * 32);
      ah[1][kcl][0] = AL_RLX(hp); ah[1][kcl][1] = AL_RLX(hp + 1);
    }

    // ---- x-phase MFMAs (ax long arrived; fills flight-0 latency) ----
    f32x4 acc[2][4];
#pragma unroll
    for (int ntl = 0; ntl < 2; ntl++)
#pragma unroll
      for (int c = 0; c < 4; c++) acc[ntl][c] = (f32x4){0.f, 0.f, 0.f, 0.f};
#pragma unroll
    for (int kc = 0; kc < 8; kc++) {
      short8 af = cv8(ax[kc]);
      acc[0][kc & 3] = __builtin_amdgcn_mfma_f32_16x16x32_bf16(af, wx[kc][0], acc[0][kc & 3], 0, 0, 0);
      acc[1][kc & 3] = __builtin_amdgcn_mfma_f32_16x16x32_bf16(af, wx[kc][1], acc[1][kc & 3], 0, 0, 0);
    }

    // ---- H-phase: consume flight g, refill into its buffer (g+2) ----
#pragma unroll
    for (int g = 0; g < 8; g++) {
      const int fb = g & 1;
#pragma unroll
      for (int kcl = 0; kcl < 4; kcl++) {
        short8 af = mk8(ah[fb][kcl][0], ah[fb][kcl][1]);
        acc[0][kcl] = __builtin_amdgcn_mfma_f32_16x16x32_bf16(af, wh[g * 4 + kcl][0], acc[0][kcl], 0, 0, 0);
        acc[1][kcl] = __builtin_amdgcn_mfma_f32_16x16x32_bf16(af, wh[g * 4 + kcl][1], acc[1][kcl], 0, 0, 0);
      }
      if (g < 6) {
#pragma unroll
        for (int kcl = 0; kcl < 4; kcl++) {
          const u64* hp = (const u64*)(Arow + ((g + 2) * 4 + kcl) * 32);
          ah[fb][kcl][0] = AL_RLX(hp); ah[fb][kcl][1] = AL_RLX(hp + 1);
        }
      }
    }

    // ---- gate combine: ntl=0 -> {i,f}, ntl=1 -> {o,c}; swap via shfl_xor(8) ----
    f32x4 g01 = (acc[0][0] + acc[0][1]) + (acc[0][2] + acc[0][3]);
    f32x4 g23 = (acc[1][0] + acc[1][1]) + (acc[1][2] + acc[1][3]);

    float pr[4];
#pragma unroll
    for (int r = 0; r < 4; r++) {
      float u0 = g01[r], u1 = g23[r];
      float v0 = __shfl_xor(u0, 8);
      float v1 = __shfl_xor(u1, 8);
      float gi = hiH ? v0 : u0, gf = hiH ? u0 : v0;
      float go = hiH ? v1 : u1, gc = hiH ? u1 : v1;
      float iv = sigf(gi + bI), fv = sigf(gf + bF);
      float ov = sigf(go + bO), ct = tanhfast(gc + bC);
      Cst[r] = fv * Cst[r] + iv * ct;
      Hst[r] = ov * tanhfast(Cst[r]);
      pr[r]  = Hst[r] * wdv;
    }

    // pred partials (plain store, unique address per (t,bj,wv))
#pragma unroll
    for (int r = 0; r < 4; r++) {
      pr[r] += __shfl_xor(pr[r], 1);
      pr[r] += __shfl_xor(pr[r], 2);
      pr[r] += __shfl_xor(pr[r], 4);
    }
    if (m16 == 0) {
      float4 st = {pr[0], pr[1], pr[2], pr[3]};
      *(float4*)(p.ppart + (((size_t)t * 32 + bj) * 4 + wv) * 64 + row0 + q * 4) = st;
    }

    // ---- publish: LDS transpose (wave-private 256B) -> 16B/lane sc1 store ----
    if (!hiH) {
#pragma unroll
      for (int r = 0; r < 4; r++)
        Hpub[wv * 128 + (q * 4 + r) * 8 + hl] = f2bf(Hst[r]);
    }
    __builtin_amdgcn_s_waitcnt(0xC07F);     // lgkmcnt(0): wave's ds writes done
    __builtin_amdgcn_wave_barrier();
    if (lane < 16) {
      const u64* src = (const u64*)(Hpub + wv * 128 + lane * 8);
      u64 lo = src[0], hi = src[1];
      u64* dst = (u64*)(Hw + (size_t)(row0 + lane) * HU + bj * 32 + wv * 8);
      AS_RLX(dst, lo); AS_RLX(dst + 1, hi);
    }
    __builtin_amdgcn_sched_barrier(0);
    __builtin_amdgcn_s_waitcnt(0x0F70);     // vmcnt(0): publish acked at LLC
    __builtin_amdgcn_sched_barrier(0);
    if (lane == 0) AS_RLX(myflag, (u32)(t + 1));
    __builtin_amdgcn_sched_barrier(0);

    // ---- x prefetch for t+1 (latency hidden under next poll) ----
    {
      const int tn = (t + 1 < SEQ) ? t + 1 : t;
#pragma unroll
      for (int kc = 0; kc < 8; kc++)
        ax[kc] = *(const uint4*)(p.xbf + ((size_t)((row0 + m16) * SEQ + tn)) * DIM
                                 + kc * 32 + q8);
    }
  }

  // finals
  if (!hiH) {
#pragma unroll
    for (int r = 0; r < 4; r++) {
      int row = row0 + q * 4 + r;
      p.Hf[row * HU + hglob] = Hst[r];
      p.Cf[row * HU + hglob] = Cst[r];
    }
  }
}

// ---------------- launch ----------------

extern "C" void kernel_launch(void* const* d_in, const int* in_sizes, int n_in,
                              void* d_out, int out_size, void* d_ws, size_t ws_size,
                              hipStream_t stream) {
  const float* inputs = (const float*)d_in[0];
  const float* H0  = (const float*)d_in[1];
  const float* C0  = (const float*)d_in[2];
  const float* Wxi = (const float*)d_in[3];
  const float* Whi = (const float*)d_in[4];
  const float* bi  = (const float*)d_in[5];
  const float* Wxf = (const float*)d_in[6];
  const float* Whf = (const float*)d_in[7];
  const float* bf_ = (const float*)d_in[8];
  const float* Wxo = (const float*)d_in[9];
  const float* Who = (const float*)d_in[10];
  const float* bo  = (const float*)d_in[11];
  const float* Wxc = (const float*)d_in[12];
  const float* Whc = (const float*)d_in[13];
  const float* bc  = (const float*)d_in[14];
  const float* Wd  = (const float*)d_in[15];
  const float* bd  = (const float*)d_in[16];

  char* ws = (char*)d_ws;
  u32*   flags = (u32*)ws;                                       // 32768 B
  u16*   Wpack = (u16*)(ws + 32768);                             // 10485760 B
  u16*   xbf   = (u16*)(ws + 32768 + 10485760);                  // 16777216 B
  u16*   Hbuf  = (u16*)(ws + 32768 + 10485760 + 16777216);       // 262144 B
  float* ppart = (float*)(ws + 32768 + 10485760 + 16777216 + 262144); // 16777216 B

  float* pred = (float*)d_out;
  float* Hf   = pred + BATCH * SEQ;
  float* Cf   = Hf + BATCH * HU;

  k_prep<<<256, 256, 0, stream>>>(H0, Hbuf, flags);
  k_xconv<<<8192, 256, 0, stream>>>(inputs, xbf);
  k_pack<<<2560, 256, 0, stream>>>(Wxi, Whi, Wxf, Whf, Wxo, Who, Wxc, Whc, Wpack);

  MainParams prm{xbf, Wpack, Hbuf, C0, Wd, bi, bf_, bo, bc, ppart, Hf, Cf, flags};
  lstm_main<<<dim3(NB), dim3(256), 0, stream>>>(prm);

  k_predsum<<<128, 256, 0, stream>>>(ppart, bd, pred);
}

// Round 8
// 2836.087 us; speedup vs baseline: 2.0007x; 2.0007x over previous
//
#include <hip/hip_runtime.h>

// LSTM forward, persistent-kernel, R8:
//   R7 post-mortem: rolling 4-kc flights expose ~500cyc x6 per step (too
//   little MFMA cover), and unthrottled 128-line polling by 512 waves floods
//   the LLC (WRITE_SIZE 2x). R8 = R6 skeleton + validated pieces only:
//   - bulk per-wave DMA staging (global_load_lds aux=17), double-buffered
//     LDS H tile (2x33KB) -> ONE __syncthreads/step (drain = DMA complete).
//   - all 4 waves poll the 32 block-flags independently (s_sleep throttled),
//     each issues its DMA on detect -> no post-poll barrier.
//   - publish via LDS transpose -> 16 lanes x 16B sc1 stores (R7-validated),
//     wave-local vmcnt(0) -> LDS arrival counter -> tid0 sets block flag
//     (no block-wide drain on the producer side).

#define NB   128
#define SEQ  512
#define BATCH 64
#define DIM  256
#define HU   1024
#define ROWU 1032   // u16 row stride: 2064 B -> b128 rows 2-way banks (free)

typedef unsigned short u16;
typedef unsigned int   u32;
typedef unsigned long long u64;
typedef __attribute__((ext_vector_type(8))) short  short8;
typedef __attribute__((ext_vector_type(4))) float  f32x4;

typedef const __attribute__((address_space(1))) void* gptr_t;
typedef __attribute__((address_space(3))) void*       lptr_t;

#define AL_RLX(p)    __hip_atomic_load((p),  __ATOMIC_RELAXED, __HIP_MEMORY_SCOPE_AGENT)
#define AS_RLX(p, v) __hip_atomic_store((p), (v), __ATOMIC_RELAXED, __HIP_MEMORY_SCOPE_AGENT)

__device__ __forceinline__ u16 f2bf(float x) {
  u32 u = __float_as_uint(x);
  u32 r = (u + 0x7FFFu + ((u >> 16) & 1u)) >> 16;   // RNE
  return (u16)r;
}
__device__ __forceinline__ float sigf(float x)  { return 1.0f / (1.0f + __expf(-x)); }
__device__ __forceinline__ float tanhfast(float x) { return 1.0f - 2.0f / (1.0f + __expf(2.0f * x)); }
__device__ __forceinline__ short8 cv8(uint4 v) {
  union { uint4 d; short8 s; } u; u.d = v; return u.s;
}

// ---------------- prologue kernels ----------------

__global__ void k_prep(const float* __restrict__ H0, u16* __restrict__ Hbuf0,
                       u32* __restrict__ flags) {
  int i = blockIdx.x * 256 + threadIdx.x;
  if (i < 2048) flags[i] = 0u;              // 128 block-flags x stride 16
  Hbuf0[i] = f2bf(H0[i]);                   // i < 65536 == BATCH*HU
}

__global__ void k_xconv(const float* __restrict__ in, u16* __restrict__ out) {
  int i = blockIdx.x * 256 + threadIdx.x;
  float4 v = ((const float4*)in)[i];
  ushort4 o;
  o.x = f2bf(v.x); o.y = f2bf(v.y); o.z = f2bf(v.z); o.w = f2bf(v.w);
  ((ushort4*)out)[i] = o;
}

// Wpack[bj(32)][nt(8)][kc(40)][lane(64)][8] bf16 : MFMA B-fragment order.
// local col c = nt*16 + (lane&15) in [0,128):
//   gate=(c>>3)&3, h = bj*32 + (c>>5)*8 + (c&7)
__global__ void k_pack(const float* __restrict__ Wxi, const float* __restrict__ Whi,
                       const float* __restrict__ Wxf, const float* __restrict__ Whf,
                       const float* __restrict__ Wxo, const float* __restrict__ Who,
                       const float* __restrict__ Wxc, const float* __restrict__ Whc,
                       u16* __restrict__ Wpack) {
  int tid  = blockIdx.x * 256 + threadIdx.x;   // < 32*8*40*64 = 655360
  int lane = tid & 63;
  int kc   = (tid >> 6) % 40;
  int nt   = ((tid >> 6) / 40) & 7;
  int bj   = (tid >> 6) / 320;
  int c    = nt * 16 + (lane & 15);
  int gate = (c >> 3) & 3;
  int h    = bj * 32 + (c >> 5) * 8 + (c & 7);
  const float* Wx = (gate == 0) ? Wxi : (gate == 1) ? Wxf : (gate == 2) ? Wxo : Wxc;
  const float* Wh = (gate == 0) ? Whi : (gate == 1) ? Whf : (gate == 2) ? Who : Whc;
  int kbase = kc * 32 + ((lane >> 4) << 3);
  u16 tmp[8];
#pragma unroll
  for (int e = 0; e < 8; e++) {
    int k = kbase + e;
    float v = (k < DIM) ? Wx[k * HU + h] : Wh[(k - DIM) * HU + h];
    tmp[e] = f2bf(v);
  }
  *(uint4*)(Wpack + (size_t)tid * 8) = *(uint4*)tmp;
}

// pred[b,t] = bd + sum_{g<128} part[t*8192 + g*64 + b];  32768 threads
__global__ void k_predsum(const float* __restrict__ part, const float* __restrict__ bd,
                          float* __restrict__ pred) {
  int i = blockIdx.x * 256 + threadIdx.x;
  int b = i & 63, t = i >> 6;
  float s = bd[0];
  const float* p0 = part + (size_t)t * NB * 64 + b;
#pragma unroll 8
  for (int jj = 0; jj < NB; jj++) s += p0[jj * 64];
  pred[b * SEQ + t] = s;
}

// ---------------- main persistent kernel ----------------

struct MainParams {
  const u16* __restrict__ xbf;     // (B,S,D) bf16
  const u16* __restrict__ Wpack;   // [32][8][40][64][8] bf16
  u16* __restrict__ Hbuf;          // [2][B][HU] bf16 (double buffer)
  const float* __restrict__ C0;
  const float* __restrict__ Wd;
  const float* __restrict__ bi;
  const float* __restrict__ bfg;
  const float* __restrict__ bo;
  const float* __restrict__ bc;
  float* __restrict__ ppart;       // [SEQ][32bj][4wv][64b] pred partials
  float* __restrict__ Hf;          // [B][HU]
  float* __restrict__ Cf;          // [B][HU]
  u32* __restrict__ flags;         // [4bb][32bj] stride-16 u32
};

__global__ __launch_bounds__(256, 1) void lstm_main(MainParams p) {
  __shared__ __align__(16) u16 Hsm[2][16 * ROWU];  // 2 x 33024 B (dbuf)
  __shared__ u16 Hpub[4 * 128];                    // per-wave publish tile
  __shared__ u32 cnt;                              // arrival counter

  const int tid  = threadIdx.x;
  const int wv   = tid >> 6, lane = tid & 63;
  const int bj   = blockIdx.x >> 2, bb = blockIdx.x & 3;
  const int q    = lane >> 4;              // row quad
  const int q8   = q * 8;                  // k sub-offset in frag
  const int m16  = lane & 15;
  const int hl   = lane & 7;
  const bool hiH = (lane & 8) != 0;        // f/c-holder half

  const int hglob = bj * 32 + wv * 8 + hl; // this thread's h column
  const int row0  = 16 * bb;               // block's first batch row

  // resident weight B-fragments: wave wv owns n-tiles {2wv, 2wv+1}, full K.
  short8 wx[8][2], wh[32][2];
  {
    const u16* wbase = p.Wpack + ((size_t)bj * 8 + 2 * wv) * (40 * 512) + lane * 8;
#pragma unroll
    for (int kc = 0; kc < 8; kc++)
#pragma unroll
      for (int ntl = 0; ntl < 2; ntl++)
        wx[kc][ntl] = *(const short8*)(wbase + ((size_t)ntl * 40 + kc) * 512);
#pragma unroll
    for (int kc = 0; kc < 32; kc++)
#pragma unroll
      for (int ntl = 0; ntl < 2; ntl++)
        wh[kc][ntl] = *(const short8*)(wbase + ((size_t)ntl * 40 + 8 + kc) * 512);
  }

  // per-thread epilogue state: 4 rows (q*4+r), one h
  const float bI = p.bi[hglob],  bF = p.bfg[hglob];
  const float bO = p.bo[hglob],  bC = p.bc[hglob];
  const float wdv = p.Wd[hglob];
  float Cst[4], Hst[4];
#pragma unroll
  for (int r = 0; r < 4; r++) {
    Cst[r] = p.C0[(row0 + q * 4 + r) * HU + hglob];
    Hst[r] = 0.f;
  }

  // x fragments for t=0
  uint4 ax[8];
#pragma unroll
  for (int kc = 0; kc < 8; kc++)
    ax[kc] = *(const uint4*)(p.xbf + ((size_t)((row0 + m16) * SEQ + 0)) * DIM
                             + kc * 32 + q8);

  if (tid == 0) cnt = 0u;
  __syncthreads();

  const u32* fbase = p.flags + (size_t)bb * 32 * 16;
  u32* myflag = p.flags + (size_t)(bb * 32 + bj) * 16;

#pragma unroll 1
  for (int t = 0; t < SEQ; t++) {
    const int rb = t & 1;
    const u16* Hr = p.Hbuf + (size_t)rb * (BATCH * HU);
    u16*       Hw = p.Hbuf + (size_t)(rb ^ 1) * (BATCH * HU);
    u16*       smb = &Hsm[t & 1][0];

    // ---- poll: every wave independently watches the 32 same-bb flags ----
    {
      const u32 tgt = (u32)t;
      while (true) {
        u32 a = AL_RLX(fbase + (size_t)(lane & 31) * 16);
        if (__all((int)(a >= tgt))) break;
        __builtin_amdgcn_s_sleep(1);
      }
    }

    // ---- DMA issue: wave wv -> segments [8wv, 8wv+8) into smb ----
#pragma unroll
    for (int i = 0; i < 8; i++) {
      int s = wv * 8 + i, row = s >> 1, half = s & 1;
      const u16* g = Hr + (size_t)(row0 + row) * HU + half * 512 + lane * 8;
      __builtin_amdgcn_global_load_lds((gptr_t)(const void*)g,
          (lptr_t)(void*)(smb + row * ROWU + half * 512), 16, 0, 17);
    }

    // ---- x-phase MFMAs (in the shadow of DMA latency) ----
    f32x4 acc[2][4];
#pragma unroll
    for (int ntl = 0; ntl < 2; ntl++)
#pragma unroll
      for (int c = 0; c < 4; c++) acc[ntl][c] = (f32x4){0.f, 0.f, 0.f, 0.f};
#pragma unroll
    for (int kc = 0; kc < 8; kc++) {
      short8 af = cv8(ax[kc]);
      acc[0][kc & 3] = __builtin_amdgcn_mfma_f32_16x16x32_bf16(af, wx[kc][0], acc[0][kc & 3], 0, 0, 0);
      acc[1][kc & 3] = __builtin_amdgcn_mfma_f32_16x16x32_bf16(af, wx[kc][1], acc[1][kc & 3], 0, 0, 0);
    }
    // ---- x prefetch for t+1 (drained by the same barrier) ----
    {
      const int tn = (t + 1 < SEQ) ? t + 1 : t;
#pragma unroll
      for (int kc = 0; kc < 8; kc++)
        ax[kc] = *(const uint4*)(p.xbf + ((size_t)((row0 + m16) * SEQ + tn)) * DIM
                                 + kc * 32 + q8);
    }

    __syncthreads();   // vmcnt(0) drain = all DMA landed; rendezvous

    // ---- H-phase MFMAs from LDS (full K per wave, 2 n-tiles) ----
#pragma unroll
    for (int kc = 0; kc < 32; kc++) {
      short8 af = *(const short8*)(smb + m16 * ROWU + kc * 32 + q8);
      acc[0][kc & 3] = __builtin_amdgcn_mfma_f32_16x16x32_bf16(af, wh[kc][0], acc[0][kc & 3], 0, 0, 0);
      acc[1][kc & 3] = __builtin_amdgcn_mfma_f32_16x16x32_bf16(af, wh[kc][1], acc[1][kc & 3], 0, 0, 0);
    }

    // ---- gate combine: ntl=0 -> {i,f}, ntl=1 -> {o,c}; swap via shfl_xor(8) ----
    f32x4 g01 = (acc[0][0] + acc[0][1]) + (acc[0][2] + acc[0][3]);
    f32x4 g23 = (acc[1][0] + acc[1][1]) + (acc[1][2] + acc[1][3]);

    float pr[4];
#pragma unroll
    for (int r = 0; r < 4; r++) {
      float u0 = g01[r], u1 = g23[r];
      float v0 = __shfl_xor(u0, 8);
      float v1 = __shfl_xor(u1, 8);
      float gi = hiH ? v0 : u0, gf = hiH ? u0 : v0;
      float go = hiH ? v1 : u1, gc = hiH ? u1 : v1;
      float iv = sigf(gi + bI), fv = sigf(gf + bF);
      float ov = sigf(go + bO), ct = tanhfast(gc + bC);
      Cst[r] = fv * Cst[r] + iv * ct;
      Hst[r] = ov * tanhfast(Cst[r]);
      pr[r]  = Hst[r] * wdv;
    }

    // pred partials (plain store, unique address per (t,bj,wv))
#pragma unroll
    for (int r = 0; r < 4; r++) {
      pr[r] += __shfl_xor(pr[r], 1);
      pr[r] += __shfl_xor(pr[r], 2);
      pr[r] += __shfl_xor(pr[r], 4);
    }
    if (m16 == 0) {
      float4 st = {pr[0], pr[1], pr[2], pr[3]};
      *(float4*)(p.ppart + (((size_t)t * 32 + bj) * 4 + wv) * 64 + row0 + q * 4) = st;
    }

    // ---- publish: wave-private LDS transpose -> 16 lanes x 16B sc1 store ----
    if (!hiH) {
#pragma unroll
      for (int r = 0; r < 4; r++)
        Hpub[wv * 128 + (q * 4 + r) * 8 + hl] = f2bf(Hst[r]);
    }
    __builtin_amdgcn_s_waitcnt(0xC07F);     // lgkmcnt(0): wave's ds writes done
    __builtin_amdgcn_wave_barrier();
    if (lane < 16) {
      const u64* src = (const u64*)(Hpub + wv * 128 + lane * 8);
      u64 lo = src[0], hi = src[1];
      u64* dst = (u64*)(Hw + (size_t)(row0 + lane) * HU + bj * 32 + wv * 8);
      AS_RLX(dst, lo); AS_RLX(dst + 1, hi);
    }
    __builtin_amdgcn_sched_barrier(0);
    __builtin_amdgcn_s_waitcnt(0x0F70);     // vmcnt(0): THIS wave's stores acked
    __builtin_amdgcn_sched_barrier(0);
    if (lane == 0)
      __hip_atomic_fetch_add(&cnt, 1u, __ATOMIC_RELAXED, __HIP_MEMORY_SCOPE_WORKGROUP);
    if (tid == 0) {
      while (__hip_atomic_load(&cnt, __ATOMIC_RELAXED, __HIP_MEMORY_SCOPE_WORKGROUP)
             < 4u * (u32)(t + 1)) {}
      AS_RLX(myflag, (u32)(t + 1));         // all 4 waves' publishes at LLC
    }
  }

  // finals
  if (!hiH) {
#pragma unroll
    for (int r = 0; r < 4; r++) {
      int row = row0 + q * 4 + r;
      p.Hf[row * HU + hglob] = Hst[r];
      p.Cf[row * HU + hglob] = Cst[r];
    }
  }
}

// ---------------- launch ----------------

extern "C" void kernel_launch(void* const* d_in, const int* in_sizes, int n_in,
                              void* d_out, int out_size, void* d_ws, size_t ws_size,
                              hipStream_t stream) {
  const float* inputs = (const float*)d_in[0];
  const float* H0  = (const float*)d_in[1];
  const float* C0  = (const float*)d_in[2];
  const float* Wxi = (const float*)d_in[3];
  const float* Whi = (const float*)d_in[4];
  const float* bi  = (const float*)d_in[5];
  const float* Wxf = (const float*)d_in[6];
  const float* Whf = (const float*)d_in[7];
  const float* bf_ = (const float*)d_in[8];
  const float* Wxo = (const float*)d_in[9];
  const float* Who = (const float*)d_in[10];
  const float* bo  = (const float*)d_in[11];
  const float* Wxc = (const float*)d_in[12];
  const float* Whc = (const float*)d_in[13];
  const float* bc  = (const float*)d_in[14];
  const float* Wd  = (const float*)d_in[15];
  const float* bd  = (const float*)d_in[16];

  char* ws = (char*)d_ws;
  u32*   flags = (u32*)ws;                                       // 8192 B
  u16*   Wpack = (u16*)(ws + 8192);                              // 10485760 B
  u16*   xbf   = (u16*)(ws + 8192 + 10485760);                   // 16777216 B
  u16*   Hbuf  = (u16*)(ws + 8192 + 10485760 + 16777216);        // 262144 B
  float* ppart = (float*)(ws + 8192 + 10485760 + 16777216 + 262144); // 16777216 B

  float* pred = (float*)d_out;
  float* Hf   = pred + BATCH * SEQ;
  float* Cf   = Hf + BATCH * HU;

  k_prep<<<256, 256, 0, stream>>>(H0, Hbuf, flags);
  k_xconv<<<8192, 256, 0, stream>>>(inputs, xbf);
  k_pack<<<2560, 256, 0, stream>>>(Wxi, Whi, Wxf, Whf, Wxo, Who, Wxc, Whc, Wpack);

  MainParams prm{xbf, Wpack, Hbuf, C0, Wd, bi, bf_, bo, bc, ppart, Hf, Cf, flags};
  lstm_main<<<dim3(NB), dim3(256), 0, stream>>>(prm);

  k_predsum<<<128, 256, 0, stream>>>(ppart, bd, pred);
}

// Round 9
// 2447.720 us; speedup vs baseline: 2.3182x; 1.1587x over previous
//
#include <hip/hip_runtime.h>

// LSTM forward, persistent-kernel, R9:
//   R8 post-mortem: producer-side LDS-cnt + tid0 unthrottled LDS spin contends
//   the LDS pipe during other waves' H-phase; u64 atomic publish doubled
//   WRITE_SIZE. R9 = R6 verbatim EXCEPT:
//   - consumer poll moved to top of loop, per-wave, s_sleep(1)-throttled
//     (kills R6's unthrottled 4096-lane poll flood + delegation hop).
//   - 2 barriers/step (mid = DMA drain, end = publish drain -> tid0 flag);
//     barriers pin waves within an iteration => single 33KB Hsm stays safe.
//   - publish (R6's 2B-store variant, measured good) issued BEFORE the ppart
//     reduction so store-ack overlaps VALU work.

#define NB   128
#define SEQ  512
#define BATCH 64
#define DIM  256
#define HU   1024
#define ROWU 1032   // u16 row stride: 2064 B -> b128 rows 2-way banks (free)

typedef unsigned short u16;
typedef unsigned int   u32;
typedef unsigned long long u64;
typedef __attribute__((ext_vector_type(8))) short  short8;
typedef __attribute__((ext_vector_type(4))) float  f32x4;

typedef const __attribute__((address_space(1))) void* gptr_t;
typedef __attribute__((address_space(3))) void*       lptr_t;

#define AL_RLX(p)    __hip_atomic_load((p),  __ATOMIC_RELAXED, __HIP_MEMORY_SCOPE_AGENT)
#define AS_RLX(p, v) __hip_atomic_store((p), (v), __ATOMIC_RELAXED, __HIP_MEMORY_SCOPE_AGENT)

__device__ __forceinline__ u16 f2bf(float x) {
  u32 u = __float_as_uint(x);
  u32 r = (u + 0x7FFFu + ((u >> 16) & 1u)) >> 16;   // RNE
  return (u16)r;
}
__device__ __forceinline__ float sigf(float x)  { return 1.0f / (1.0f + __expf(-x)); }
__device__ __forceinline__ float tanhfast(float x) { return 1.0f - 2.0f / (1.0f + __expf(2.0f * x)); }
__device__ __forceinline__ short8 cv8(uint4 v) {
  union { uint4 d; short8 s; } u; u.d = v; return u.s;
}

// ---------------- prologue kernels ----------------

__global__ void k_prep(const float* __restrict__ H0, u16* __restrict__ Hbuf0,
                       u32* __restrict__ flags) {
  int i = blockIdx.x * 256 + threadIdx.x;
  if (i < 2048) flags[i] = 0u;              // 128 block-flags x stride 16
  Hbuf0[i] = f2bf(H0[i]);                   // i < 65536 == BATCH*HU
}

__global__ void k_xconv(const float* __restrict__ in, u16* __restrict__ out) {
  int i = blockIdx.x * 256 + threadIdx.x;
  float4 v = ((const float4*)in)[i];
  ushort4 o;
  o.x = f2bf(v.x); o.y = f2bf(v.y); o.z = f2bf(v.z); o.w = f2bf(v.w);
  ((ushort4*)out)[i] = o;
}

// Wpack[bj(32)][nt(8)][kc(40)][lane(64)][8] bf16 : MFMA B-fragment order.
// local col c = nt*16 + (lane&15) in [0,128):
//   gate=(c>>3)&3, h = bj*32 + (c>>5)*8 + (c&7)
__global__ void k_pack(const float* __restrict__ Wxi, const float* __restrict__ Whi,
                       const float* __restrict__ Wxf, const float* __restrict__ Whf,
                       const float* __restrict__ Wxo, const float* __restrict__ Who,
                       const float* __restrict__ Wxc, const float* __restrict__ Whc,
                       u16* __restrict__ Wpack) {
  int tid  = blockIdx.x * 256 + threadIdx.x;   // < 32*8*40*64 = 655360
  int lane = tid & 63;
  int kc   = (tid >> 6) % 40;
  int nt   = ((tid >> 6) / 40) & 7;
  int bj   = (tid >> 6) / 320;
  int c    = nt * 16 + (lane & 15);
  int gate = (c >> 3) & 3;
  int h    = bj * 32 + (c >> 5) * 8 + (c & 7);
  const float* Wx = (gate == 0) ? Wxi : (gate == 1) ? Wxf : (gate == 2) ? Wxo : Wxc;
  const float* Wh = (gate == 0) ? Whi : (gate == 1) ? Whf : (gate == 2) ? Who : Whc;
  int kbase = kc * 32 + ((lane >> 4) << 3);
  u16 tmp[8];
#pragma unroll
  for (int e = 0; e < 8; e++) {
    int k = kbase + e;
    float v = (k < DIM) ? Wx[k * HU + h] : Wh[(k - DIM) * HU + h];
    tmp[e] = f2bf(v);
  }
  *(uint4*)(Wpack + (size_t)tid * 8) = *(uint4*)tmp;
}

// pred[b,t] = bd + sum_{g<128} part[t*8192 + g*64 + b];  32768 threads
__global__ void k_predsum(const float* __restrict__ part, const float* __restrict__ bd,
                          float* __restrict__ pred) {
  int i = blockIdx.x * 256 + threadIdx.x;
  int b = i & 63, t = i >> 6;
  float s = bd[0];
  const float* p0 = part + (size_t)t * NB * 64 + b;
#pragma unroll 8
  for (int jj = 0; jj < NB; jj++) s += p0[jj * 64];
  pred[b * SEQ + t] = s;
}

// ---------------- main persistent kernel ----------------

struct MainParams {
  const u16* __restrict__ xbf;     // (B,S,D) bf16
  const u16* __restrict__ Wpack;   // [32][8][40][64][8] bf16
  u16* __restrict__ Hbuf;          // [2][B][HU] bf16 (double buffer)
  const float* __restrict__ C0;
  const float* __restrict__ Wd;
  const float* __restrict__ bi;
  const float* __restrict__ bfg;
  const float* __restrict__ bo;
  const float* __restrict__ bc;
  float* __restrict__ ppart;       // [SEQ][32bj][4wv][64b] pred partials
  float* __restrict__ Hf;          // [B][HU]
  float* __restrict__ Cf;          // [B][HU]
  u32* __restrict__ flags;         // [4bb][32bj] stride-16 u32
};

__global__ __launch_bounds__(256, 1) void lstm_main(MainParams p) {
  __shared__ __align__(16) u16 Hsm[16 * ROWU];   // 33024 B

  const int tid  = threadIdx.x;
  const int wv   = tid >> 6, lane = tid & 63;
  const int bj   = blockIdx.x >> 2, bb = blockIdx.x & 3;
  const int q    = lane >> 4;              // row quad
  const int q8   = q * 8;                  // k sub-offset in frag
  const int m16  = lane & 15;
  const int hl   = lane & 7;
  const bool hiH = (lane & 8) != 0;        // f/c-holder half

  const int hglob = bj * 32 + wv * 8 + hl; // this thread's h column
  const int row0  = 16 * bb;               // block's first batch row

  // resident weight B-fragments: wave wv owns n-tiles {2wv, 2wv+1}, full K.
  short8 wx[8][2], wh[32][2];
  {
    const u16* wbase = p.Wpack + ((size_t)bj * 8 + 2 * wv) * (40 * 512) + lane * 8;
#pragma unroll
    for (int kc = 0; kc < 8; kc++)
#pragma unroll
      for (int ntl = 0; ntl < 2; ntl++)
        wx[kc][ntl] = *(const short8*)(wbase + ((size_t)ntl * 40 + kc) * 512);
#pragma unroll
    for (int kc = 0; kc < 32; kc++)
#pragma unroll
      for (int ntl = 0; ntl < 2; ntl++)
        wh[kc][ntl] = *(const short8*)(wbase + ((size_t)ntl * 40 + 8 + kc) * 512);
  }

  // per-thread epilogue state: 4 rows (q*4+r), one h
  const float bI = p.bi[hglob],  bF = p.bfg[hglob];
  const float bO = p.bo[hglob],  bC = p.bc[hglob];
  const float wdv = p.Wd[hglob];
  float Cst[4], Hst[4];
#pragma unroll
  for (int r = 0; r < 4; r++) {
    Cst[r] = p.C0[(row0 + q * 4 + r) * HU + hglob];
    Hst[r] = 0.f;
  }

  // x fragments for t=0
  uint4 ax[8];
#pragma unroll
  for (int kc = 0; kc < 8; kc++)
    ax[kc] = *(const uint4*)(p.xbf + ((size_t)((row0 + m16) * SEQ + 0)) * DIM
                             + kc * 32 + q8);

  const u32* fbase = p.flags + (size_t)bb * 32 * 16;
  u32* myflag = p.flags + (size_t)(bb * 32 + bj) * 16;

#pragma unroll 1
  for (int t = 0; t < SEQ; t++) {
    const int rb = t & 1;
    const u16* Hr = p.Hbuf + (size_t)rb * (BATCH * HU);
    u16*       Hw = p.Hbuf + (size_t)(rb ^ 1) * (BATCH * HU);

    // ---- per-wave throttled poll: H_t ready when all 32 same-bb flags >= t ----
    {
      const u32 tgt = (u32)t;
      while (true) {
        u32 a = AL_RLX(fbase + (size_t)(lane & 31) * 16);
        if (__all((int)(a >= tgt))) break;
        __builtin_amdgcn_s_sleep(1);
      }
    }

    // ---- DMA issue: wave wv -> segments [8wv, 8wv+8) into Hsm ----
#pragma unroll
    for (int i = 0; i < 8; i++) {
      int s = wv * 8 + i, row = s >> 1, half = s & 1;
      const u16* g = Hr + (size_t)(row0 + row) * HU + half * 512 + lane * 8;
      __builtin_amdgcn_global_load_lds((gptr_t)(const void*)g,
          (lptr_t)(void*)(Hsm + row * ROWU + half * 512), 16, 0, 17);
    }

    // ---- x-phase MFMAs (in the shadow of DMA latency) ----
    f32x4 acc[2][4];
#pragma unroll
    for (int ntl = 0; ntl < 2; ntl++)
#pragma unroll
      for (int c = 0; c < 4; c++) acc[ntl][c] = (f32x4){0.f, 0.f, 0.f, 0.f};
#pragma unroll
    for (int kc = 0; kc < 8; kc++) {
      short8 af = cv8(ax[kc]);
      acc[0][kc & 3] = __builtin_amdgcn_mfma_f32_16x16x32_bf16(af, wx[kc][0], acc[0][kc & 3], 0, 0, 0);
      acc[1][kc & 3] = __builtin_amdgcn_mfma_f32_16x16x32_bf16(af, wx[kc][1], acc[1][kc & 3], 0, 0, 0);
    }
    // ---- x prefetch for t+1 (drained by the mid barrier) ----
    {
      const int tn = (t + 1 < SEQ) ? t + 1 : t;
#pragma unroll
      for (int kc = 0; kc < 8; kc++)
        ax[kc] = *(const uint4*)(p.xbf + ((size_t)((row0 + m16) * SEQ + tn)) * DIM
                                 + kc * 32 + q8);
    }

    __syncthreads();   // vmcnt(0) drain = all DMA landed; mid rendezvous

    // ---- H-phase MFMAs from LDS (full K per wave, 2 n-tiles) ----
#pragma unroll
    for (int kc = 0; kc < 32; kc++) {
      short8 af = *(const short8*)(Hsm + m16 * ROWU + kc * 32 + q8);
      acc[0][kc & 3] = __builtin_amdgcn_mfma_f32_16x16x32_bf16(af, wh[kc][0], acc[0][kc & 3], 0, 0, 0);
      acc[1][kc & 3] = __builtin_amdgcn_mfma_f32_16x16x32_bf16(af, wh[kc][1], acc[1][kc & 3], 0, 0, 0);
    }

    // ---- gate combine: ntl=0 -> {i,f}, ntl=1 -> {o,c}; swap via shfl_xor(8) ----
    f32x4 g01 = (acc[0][0] + acc[0][1]) + (acc[0][2] + acc[0][3]);
    f32x4 g23 = (acc[1][0] + acc[1][1]) + (acc[1][2] + acc[1][3]);

    float pr[4];
#pragma unroll
    for (int r = 0; r < 4; r++) {
      float u0 = g01[r], u1 = g23[r];
      float v0 = __shfl_xor(u0, 8);
      float v1 = __shfl_xor(u1, 8);
      float gi = hiH ? v0 : u0, gf = hiH ? u0 : v0;
      float go = hiH ? v1 : u1, gc = hiH ? u1 : v1;
      float iv = sigf(gi + bI), fv = sigf(gf + bF);
      float ov = sigf(go + bO), ct = tanhfast(gc + bC);
      Cst[r] = fv * Cst[r] + iv * ct;
      Hst[r] = ov * tanhfast(Cst[r]);
      pr[r]  = Hst[r] * wdv;
    }

    // ---- publish H_t+1 FIRST (2B sc1 stores; ack overlaps ppart VALU) ----
    if (!hiH) {
#pragma unroll
      for (int r = 0; r < 4; r++)
        AS_RLX(Hw + (size_t)(row0 + q * 4 + r) * HU + hglob, f2bf(Hst[r]));
    }

    // ---- pred partials (plain store, unique address per (t,bj,wv)) ----
#pragma unroll
    for (int r = 0; r < 4; r++) {
      pr[r] += __shfl_xor(pr[r], 1);
      pr[r] += __shfl_xor(pr[r], 2);
      pr[r] += __shfl_xor(pr[r], 4);
    }
    if (m16 == 0) {
      float4 st = {pr[0], pr[1], pr[2], pr[3]};
      *(float4*)(p.ppart + (((size_t)t * 32 + bj) * 4 + wv) * 64 + row0 + q * 4) = st;
    }

    __syncthreads();   // vmcnt(0) drain: every wave's publish acked at LLC
    if (tid == 0) AS_RLX(myflag, (u32)(t + 1));
  }

  // finals
  if (!hiH) {
#pragma unroll
    for (int r = 0; r < 4; r++) {
      int row = row0 + q * 4 + r;
      p.Hf[row * HU + hglob] = Hst[r];
      p.Cf[row * HU + hglob] = Cst[r];
    }
  }
}

// ---------------- launch ----------------

extern "C" void kernel_launch(void* const* d_in, const int* in_sizes, int n_in,
                              void* d_out, int out_size, void* d_ws, size_t ws_size,
                              hipStream_t stream) {
  const float* inputs = (const float*)d_in[0];
  const float* H0  = (const float*)d_in[1];
  const float* C0  = (const float*)d_in[2];
  const float* Wxi = (const float*)d_in[3];
  const float* Whi = (const float*)d_in[4];
  const float* bi  = (const float*)d_in[5];
  const float* Wxf = (const float*)d_in[6];
  const float* Whf = (const float*)d_in[7];
  const float* bf_ = (const float*)d_in[8];
  const float* Wxo = (const float*)d_in[9];
  const float* Who = (const float*)d_in[10];
  const float* bo  = (const float*)d_in[11];
  const float* Wxc = (const float*)d_in[12];
  const float* Whc = (const float*)d_in[13];
  const float* bc  = (const float*)d_in[14];
  const float* Wd  = (const float*)d_in[15];
  const float* bd  = (const float*)d_in[16];

  char* ws = (char*)d_ws;
  u32*   flags = (u32*)ws;                                       // 8192 B
  u16*   Wpack = (u16*)(ws + 8192);                              // 10485760 B
  u16*   xbf   = (u16*)(ws + 8192 + 10485760);                   // 16777216 B
  u16*   Hbuf  = (u16*)(ws + 8192 + 10485760 + 16777216);        // 262144 B
  float* ppart = (float*)(ws + 8192 + 10485760 + 16777216 + 262144); // 16777216 B

  float* pred = (float*)d_out;
  float* Hf   = pred + BATCH * SEQ;
  float* Cf   = Hf + BATCH * HU;

  k_prep<<<256, 256, 0, stream>>>(H0, Hbuf, flags);
  k_xconv<<<8192, 256, 0, stream>>>(inputs, xbf);
  k_pack<<<2560, 256, 0, stream>>>(Wxi, Whi, Wxf, Whf, Wxo, Who, Wxc, Whc, Wpack);

  MainParams prm{xbf, Wpack, Hbuf, C0, Wd, bi, bf_, bo, bc, ppart, Hf, Cf, flags};
  lstm_main<<<dim3(NB), dim3(256), 0, stream>>>(prm);

  k_predsum<<<128, 256, 0, stream>>>(ppart, bd, pred);
}